// Round 1
// baseline (5133.427 us; speedup 1.0000x reference)
//
#include <hip/hip_runtime.h>
#include <stdint.h>

#define BN_ 8192
#define DN_ 1024
#define INV_T 10.0f
#define SHIFT_ 460.0f

typedef __attribute__((ext_vector_type(8))) short bf16x8;
typedef __attribute__((ext_vector_type(4))) float f32x4;

__device__ __forceinline__ float bf2f(unsigned short u) {
  return __uint_as_float(((unsigned int)u) << 16);
}
__device__ __forceinline__ unsigned short f2bf(float f) {
  unsigned int u = __float_as_uint(f);
  return (unsigned short)((u + 0x7FFFu + ((u >> 16) & 1u)) >> 16);
}

// ---------------- prep: fp32 -> bf16 cast + row sum-of-squares ----------------
__global__ void prep_kernel(const float* __restrict__ gen, const float* __restrict__ pos,
                            unsigned short* __restrict__ gen_h, unsigned short* __restrict__ pos_h,
                            float* __restrict__ gn2, float* __restrict__ pn2) {
  int b = blockIdx.x;
  const float* src; unsigned short* dst; float* n2; int row;
  if (b < BN_) { src = gen; dst = gen_h; n2 = gn2; row = b; }
  else         { src = pos; dst = pos_h; n2 = pn2; row = b - BN_; }
  int t = threadIdx.x;
  float4 v = ((const float4*)(src + (size_t)row * DN_))[t];
  float ss = v.x * v.x + v.y * v.y + v.z * v.z + v.w * v.w;
  ushort4 o;
  o.x = f2bf(v.x); o.y = f2bf(v.y); o.z = f2bf(v.z); o.w = f2bf(v.w);
  ((ushort4*)(dst + (size_t)row * DN_))[t] = o;
#pragma unroll
  for (int m = 1; m < 64; m <<= 1) ss += __shfl_xor(ss, m);
  __shared__ float red[4];
  if ((t & 63) == 0) red[t >> 6] = ss;
  __syncthreads();
  if (t == 0) n2[row] = red[0] + red[1] + red[2] + red[3];
}

// ---------------- transpose: fp32 [8192][1024] -> bf16 [1024][8192] ----------------
__global__ void transpose_kernel(const float* __restrict__ gen, const float* __restrict__ pos,
                                 unsigned short* __restrict__ genT, unsigned short* __restrict__ posT) {
  __shared__ float tile[64][65];
  int b = blockIdx.x;
  const float* src; unsigned short* dst;
  if (b < 2048) { src = gen; dst = genT; }
  else          { src = pos; dst = posT; b -= 2048; }
  int tj = b >> 4, td = b & 15;
  int t = threadIdx.x;
#pragma unroll
  for (int it = 0; it < 16; ++it) {
    int idx = it * 256 + t;
    int r = idx >> 6, c = idx & 63;
    tile[r][c] = src[(size_t)(tj * 64 + r) * DN_ + td * 64 + c];
  }
  __syncthreads();
#pragma unroll
  for (int it = 0; it < 16; ++it) {
    int idx = it * 256 + t;
    int d = idx >> 6, j = idx & 63;
    dst[(size_t)(td * 64 + d) * BN_ + tj * 64 + j] = f2bf(tile[j][d]);
  }
}

// ---------------- flash kernel: O_i = sum_j exp(460 - 10*dist_ij) v_j ; l_i = sum_j ... ----------------
// i-block = 32 rows, 4 waves. Wave w: score rows half mh=w>>1, score col half nh=w&1.
// PV: wave w owns output d-range [w*256, w*256+256).
template <bool MASK>
__launch_bounds__(256, 1)
__global__ void flash_kernel(const unsigned short* __restrict__ Qh,   // [8192][1024] bf16
                             const unsigned short* __restrict__ Kh,   // [8192][1024] bf16
                             const unsigned short* __restrict__ VT,   // [1024][8192] bf16 (transposed V)
                             const float* __restrict__ qn2,
                             const float* __restrict__ kn2,
                             const float* __restrict__ genf,          // fp32 gen
                             unsigned short* __restrict__ attr,       // bf16 [8192][1024]
                             float* __restrict__ gs) {
  __shared__ __align__(16) unsigned short Ks[2][64][136];  // dbuf K chunk: 64 j x 128 d (+8 pad)
  __shared__ __align__(16) unsigned short Ps[32][72];      // P tile: 32 i x 64 j (+8 pad)
  __shared__ float kn2s[64];
  __shared__ float qn2s[32];
  __shared__ float larr[32];
  __shared__ float rsqA[32];
  __shared__ float rsqB[32];

  const int t = threadIdx.x;
  const int w = t >> 6;
  const int lane = t & 63;
  const int l15 = lane & 15;
  const int quad = lane >> 4;
  const int mh = w >> 1;
  const int nh = w & 1;
  const int i0 = blockIdx.x * 32;

  if (t < 32) { qn2s[t] = qn2[i0 + t]; larr[t] = 0.f; rsqA[t] = 0.f; rsqB[t] = 0.f; }

  // Q fragments in registers: this wave's 16 rows, full K=1024.
  // A-frag layout: m = lane&15, k = quad*8 + e
  bf16x8 qf[32];
  {
    const unsigned short* qrow = Qh + (size_t)(i0 + mh * 16 + l15) * DN_ + quad * 8;
#pragma unroll
    for (int ks = 0; ks < 32; ++ks) qf[ks] = *(const bf16x8*)(qrow + ks * 32);
  }

  const f32x4 fzero = {0.f, 0.f, 0.f, 0.f};
  f32x4 acc[2][16];
#pragma unroll
  for (int a = 0; a < 2; ++a)
#pragma unroll
    for (int b = 0; b < 16; ++b) acc[a][b] = fzero;
  float lacc[4] = {0.f, 0.f, 0.f, 0.f};

  const int sj = t >> 4;          // staging row part 0..15
  const int sd = (t & 15) * 8;    // staging col offset (bf16 elems)

  for (int jt = 0; jt < BN_ / 64; ++jt) {
    const int j0 = jt * 64;

    // ---------- phase A: S(32x64) = Q @ K_tile^T over K=1024, chunks of 128, dbuf+prefetch ----------
    f32x4 accs0 = fzero, accs1 = fzero;
    uint4 preA[4], preB[4];
#pragma unroll
    for (int u = 0; u < 4; ++u)
      preA[u] = *(const uint4*)(Kh + (size_t)(j0 + u * 16 + sj) * DN_ + 0 * 128 + sd);
#pragma unroll
    for (int u = 0; u < 4; ++u)
      preB[u] = *(const uint4*)(Kh + (size_t)(j0 + u * 16 + sj) * DN_ + 1 * 128 + sd);
    if (t < 64) kn2s[t] = kn2[j0 + t];

#pragma unroll
    for (int dc = 0; dc < 8; ++dc) {
      uint4* pre = (dc & 1) ? preB : preA;
#pragma unroll
      for (int u = 0; u < 4; ++u)
        *(uint4*)(&Ks[dc & 1][u * 16 + sj][sd]) = pre[u];
      __syncthreads();
      if (dc + 2 < 8) {
#pragma unroll
        for (int u = 0; u < 4; ++u)
          pre[u] = *(const uint4*)(Kh + (size_t)(j0 + u * 16 + sj) * DN_ + (dc + 2) * 128 + sd);
      }
#pragma unroll
      for (int ks = 0; ks < 4; ++ks) {
        bf16x8 a  = qf[dc * 4 + ks];
        bf16x8 b0 = *(const bf16x8*)(&Ks[dc & 1][nh * 32 + l15][ks * 32 + quad * 8]);
        bf16x8 b1 = *(const bf16x8*)(&Ks[dc & 1][nh * 32 + 16 + l15][ks * 32 + quad * 8]);
        accs0 = __builtin_amdgcn_mfma_f32_16x16x32_bf16(a, b0, accs0, 0, 0, 0);
        accs1 = __builtin_amdgcn_mfma_f32_16x16x32_bf16(a, b1, accs1, 0, 0, 0);
      }
      __syncthreads();
    }

    // ---------- phase B: scores -> P = exp(SHIFT - 10*dist), write bf16 P tile ----------
#pragma unroll
    for (int nt = 0; nt < 2; ++nt) {
      f32x4 av = nt ? accs1 : accs0;
      int jcol = nh * 32 + nt * 16 + l15;
      float kn = kn2s[jcol];
#pragma unroll
      for (int reg = 0; reg < 4; ++reg) {
        int r = mh * 16 + quad * 4 + reg;  // C-layout: row = quad*4 + reg
        float d2 = qn2s[r] + kn - 2.0f * av[reg];
        float dist = sqrtf(fmaxf(d2, 0.0f));
        float sc = SHIFT_ - dist * INV_T;
        float p = __expf(sc);
        if (MASK && (i0 + r) == (j0 + jcol)) p = 0.0f;
        lacc[reg] += p;
        Ps[r][jcol] = f2bf(p);
      }
    }
    __syncthreads();

    // ---------- phase C: O(32x1024) += P(32x64) @ V(64x1024), V B-frags direct from global ----------
    const unsigned short* vbase = VT + (size_t)(w * 256 + l15) * BN_ + j0 + quad * 8;
#pragma unroll
    for (int ks = 0; ks < 2; ++ks) {
      bf16x8 a0 = *(const bf16x8*)(&Ps[l15][ks * 32 + quad * 8]);
      bf16x8 a1 = *(const bf16x8*)(&Ps[16 + l15][ks * 32 + quad * 8]);
#pragma unroll
      for (int nt2 = 0; nt2 < 16; ++nt2) {
        bf16x8 bv = *(const bf16x8*)(vbase + (size_t)nt2 * 16 * BN_ + ks * 32);
        acc[0][nt2] = __builtin_amdgcn_mfma_f32_16x16x32_bf16(a0, bv, acc[0][nt2], 0, 0, 0);
        acc[1][nt2] = __builtin_amdgcn_mfma_f32_16x16x32_bf16(a1, bv, acc[1][nt2], 0, 0, 0);
      }
    }
  }

  // ---------- epilogue ----------
  // finalize l per row (both nh waves contribute)
#pragma unroll
  for (int reg = 0; reg < 4; ++reg) {
    float v = lacc[reg];
    v += __shfl_xor(v, 1); v += __shfl_xor(v, 2);
    v += __shfl_xor(v, 4); v += __shfl_xor(v, 8);
    if (l15 == 0) atomicAdd(&larr[mh * 16 + quad * 4 + reg], v);
  }
  __syncthreads();

#pragma unroll
  for (int mt = 0; mt < 2; ++mt) {
#pragma unroll
    for (int reg = 0; reg < 4; ++reg) {
      const int r = mt * 16 + quad * 4 + reg;
      const float invl = 1.0f / larr[r];
      const size_t rowoff = (size_t)(i0 + r) * DN_ + w * 256 + l15;
      float sa = 0.f, sb = 0.f;
#pragma unroll
      for (int nt2 = 0; nt2 < 16; ++nt2) {
        int dcol = nt2 * 16;
        float o = acc[mt][nt2][reg] * invl;
        float g = genf[rowoff + dcol];
        float res = o - g;  // attraction or repulsion element
        if (!MASK) {
          attr[rowoff + dcol] = f2bf(res);
          sa += res * res;
        } else {
          float av = bf2f(attr[rowoff + dcol]);
          float dr = av - res;  // drift = attraction - repulsion
          sa += res * res;
          sb += dr * dr;
        }
      }
      sa += __shfl_xor(sa, 1); sa += __shfl_xor(sa, 2);
      sa += __shfl_xor(sa, 4); sa += __shfl_xor(sa, 8);
      if (MASK) {
        sb += __shfl_xor(sb, 1); sb += __shfl_xor(sb, 2);
        sb += __shfl_xor(sb, 4); sb += __shfl_xor(sb, 8);
      }
      if (l15 == 0) {
        atomicAdd(&rsqA[r], sa);
        if (MASK) atomicAdd(&rsqB[r], sb);
      }
    }
  }
  __syncthreads();
  if (t < 32) {
    if (!MASK) {
      atomicAdd(&gs[2], sqrtf(rsqA[t]));       // sum ||attraction_i||
    } else {
      atomicAdd(&gs[3], sqrtf(rsqA[t]));       // sum ||repulsion_i||
      atomicAdd(&gs[1], sqrtf(rsqB[t]));       // sum ||drift_i||
      atomicAdd(&gs[0], rsqB[t]);              // sum drift^2 (loss numerator)
    }
  }
}

__global__ void finalize_kernel(const float* __restrict__ gs, float* __restrict__ out) {
  int t = threadIdx.x;
  if (t == 0) out[0] = gs[0] / (8192.0f * 1024.0f);
  if (t == 1) out[1] = gs[1] / 8192.0f;
  if (t == 2) out[2] = gs[2] / 8192.0f;
  if (t == 3) out[3] = gs[3] / 8192.0f;
}

extern "C" void kernel_launch(void* const* d_in, const int* in_sizes, int n_in,
                              void* d_out, int out_size, void* d_ws, size_t ws_size,
                              hipStream_t stream) {
  const float* gen = (const float*)d_in[0];
  const float* pos = (const float*)d_in[1];
  char* ws = (char*)d_ws;
  const size_t MB = (size_t)1 << 20;
  unsigned short* gen_h = (unsigned short*)(ws + 0 * MB);    // 16 MB
  unsigned short* pos_h = (unsigned short*)(ws + 16 * MB);   // 16 MB
  unsigned short* genT  = (unsigned short*)(ws + 32 * MB);   // 16 MB
  unsigned short* posT  = (unsigned short*)(ws + 48 * MB);   // 16 MB
  unsigned short* attr  = (unsigned short*)(ws + 64 * MB);   // 16 MB
  float* gn2 = (float*)(ws + 80 * MB);                       // 32 KB
  float* pn2 = (float*)(ws + 80 * MB + 32768);               // 32 KB
  float* gs  = (float*)(ws + 80 * MB + 65536);               // 16 B accumulators

  hipMemsetAsync(gs, 0, 4 * sizeof(float), stream);
  prep_kernel<<<dim3(16384), dim3(256), 0, stream>>>(gen, pos, gen_h, pos_h, gn2, pn2);
  transpose_kernel<<<dim3(4096), dim3(256), 0, stream>>>(gen, pos, genT, posT);
  // attraction: Q=gen, K/V=pos
  flash_kernel<false><<<dim3(256), dim3(256), 0, stream>>>(gen_h, pos_h, posT, gn2, pn2, gen, attr, gs);
  // repulsion: Q=gen, K/V=gen, diagonal masked; combines with stored attraction
  flash_kernel<true><<<dim3(256), dim3(256), 0, stream>>>(gen_h, gen_h, genT, gn2, gn2, gen, attr, gs);
  finalize_kernel<<<dim3(1), dim3(64), 0, stream>>>(gs, (float*)d_out);
}